// Round 6
// baseline (1185.683 us; speedup 1.0000x reference)
//
#include <hip/hip_runtime.h>

#define D 128
#define H 256
#define NBLK 512          // partition blocks
#define BUCKSH 8          // bucket = dst >> 8  (256 nodes/bucket)

typedef _Float16 half8 __attribute__((ext_vector_type(8)));
typedef _Float16 half4 __attribute__((ext_vector_type(4)));
typedef float floatx4 __attribute__((ext_vector_type(4)));

// ======== multi-block exclusive scan (of M ints) ========
__global__ __launch_bounds__(256) void scan_part(const int* __restrict__ cnt,
                                                 int* __restrict__ bsum, int N){
  int base = blockIdx.x*1024;
  int tid = threadIdx.x;
  int idx = base + tid*4;
  int4 v = {0,0,0,0};
  if (idx + 3 < N) v = *(const int4*)(cnt + idx);
  else {
    if (idx   < N) v.x = cnt[idx];
    if (idx+1 < N) v.y = cnt[idx+1];
    if (idx+2 < N) v.z = cnt[idx+2];
    if (idx+3 < N) v.w = cnt[idx+3];
  }
  int s = v.x + v.y + v.z + v.w;
  #pragma unroll
  for (int off = 32; off > 0; off >>= 1) s += __shfl_down(s, off, 64);
  __shared__ int ws[4];
  int lane = tid & 63, wave = tid >> 6;
  if (lane == 0) ws[wave] = s;
  __syncthreads();
  if (tid == 0) bsum[blockIdx.x] = ws[0] + ws[1] + ws[2] + ws[3];
}

__global__ __launch_bounds__(1024) void scan_bsums(const int* __restrict__ bsum,
                                                   int* __restrict__ bbase,
                                                   int* __restrict__ total_out, int nb, int N){
  __shared__ int sh[1024];
  int tid = threadIdx.x;
  int v = (tid < nb) ? bsum[tid] : 0;
  sh[tid] = v;
  __syncthreads();
  #pragma unroll
  for (int off = 1; off < 1024; off <<= 1){
    int t = 0;
    if (tid >= off) t = sh[tid - off];
    __syncthreads();
    if (tid >= off) sh[tid] += t;
    __syncthreads();
  }
  if (tid < nb) bbase[tid] = sh[tid] - v;
  if (tid == 0) total_out[N] = sh[1023];   // grand total at [N]
}

__global__ __launch_bounds__(256) void scan_emit(const int* __restrict__ cnt,
                                                 const int* __restrict__ bbase,
                                                 int* __restrict__ outp, int N){
  int base = blockIdx.x*1024;
  int tid = threadIdx.x;
  int idx = base + tid*4;
  int4 v = {0,0,0,0};
  if (idx + 3 < N) v = *(const int4*)(cnt + idx);
  else {
    if (idx   < N) v.x = cnt[idx];
    if (idx+1 < N) v.y = cnt[idx+1];
    if (idx+2 < N) v.z = cnt[idx+2];
    if (idx+3 < N) v.w = cnt[idx+3];
  }
  int s = v.x + v.y + v.z + v.w;
  int lane = tid & 63, wave = tid >> 6;
  int incl = s;
  #pragma unroll
  for (int off = 1; off < 64; off <<= 1){
    int t = __shfl_up(incl, off, 64);
    if (lane >= off) incl += t;
  }
  __shared__ int ws[4];
  if (lane == 63) ws[wave] = incl;
  __syncthreads();
  int woff = 0;
  #pragma unroll
  for (int w = 0; w < 4; ++w) if (w < wave) woff += ws[w];
  int off0 = bbase[blockIdx.x] + woff + (incl - s);
  if (idx   < N) outp[idx]   = off0;
  if (idx+1 < N) outp[idx+1] = off0 + v.x;
  if (idx+2 < N) outp[idx+2] = off0 + v.x + v.y;
  if (idx+3 < N) outp[idx+3] = off0 + v.x + v.y + v.z;
}

// ======== 3-pass CSR partition build ========
// Pass A: per-(bucket, block) counts -> cntBB[bucket*NBLK + blk]
__global__ __launch_bounds__(256) void part_count(const int* __restrict__ dst,
                                                  int* __restrict__ cntBB,
                                                  int E, int chunk, int nbuck){
  __shared__ int lc[512];
  int b = blockIdx.x;
  for (int i = threadIdx.x; i < nbuck; i += 256) lc[i] = 0;
  __syncthreads();
  int e0 = b*chunk, e1 = min(e0 + chunk, E);
  for (int e = e0 + threadIdx.x; e < e1; e += 256)
    atomicAdd(&lc[dst[e] >> BUCKSH], 1);
  __syncthreads();
  for (int i = threadIdx.x; i < nbuck; i += 256) cntBB[i*NBLK + b] = lc[i];
}

// Pass B: bin edges into bucket-ordered staging (contiguous per-(block,bucket) segments)
__global__ __launch_bounds__(256) void part_bin(const int* __restrict__ src,
                                                const int* __restrict__ dst,
                                                const int* __restrict__ ea,
                                                const int* __restrict__ baseBB,
                                                uint2* __restrict__ staged,
                                                int E, int chunk, int nbuck){
  __shared__ int run[512];
  int b = blockIdx.x;
  for (int i = threadIdx.x; i < nbuck; i += 256) run[i] = baseBB[i*NBLK + b];
  __syncthreads();
  int e0 = b*chunk, e1 = min(e0 + chunk, E);
  for (int e = e0 + threadIdx.x; e < e1; e += 256){
    int d = dst[e];
    unsigned pv = ((unsigned)(ea[2*e]*3 + ea[2*e+1]) << 20) | (unsigned)src[e];
    int pos = atomicAdd(&run[d >> BUCKSH], 1);
    uint2 s; s.x = pv; s.y = (unsigned)d;
    staged[pos] = s;
  }
}

// Pass C: per-bucket emit: derive rowptr + place packed within L2-resident window
__global__ __launch_bounds__(256) void part_emit(const uint2* __restrict__ staged,
                                                 const int* __restrict__ baseBB,
                                                 unsigned* __restrict__ packed,
                                                 int* __restrict__ rowptr,
                                                 int N, int E, int nbuck, int M){
  __shared__ int ncnt[256];
  __shared__ int sscan[256];
  __shared__ int basep[256];
  __shared__ int cur[256];
  int k = blockIdx.x;
  int tid = threadIdx.x;
  int bstart = baseBB[k*NBLK];
  int bend = (k+1 < nbuck) ? baseBB[(k+1)*NBLK] : baseBB[M];   // baseBB[M] = E
  ncnt[tid] = 0; cur[tid] = 0;
  __syncthreads();
  for (int j = bstart + tid; j < bend; j += 256)
    atomicAdd(&ncnt[staged[j].y & 255], 1);
  __syncthreads();
  int v = ncnt[tid];
  sscan[tid] = v;
  __syncthreads();
  #pragma unroll
  for (int off = 1; off < 256; off <<= 1){
    int t = (tid >= off) ? sscan[tid-off] : 0;
    __syncthreads();
    sscan[tid] += t;
    __syncthreads();
  }
  int excl = sscan[tid] - v;                 // exclusive within bucket
  basep[tid] = bstart + excl;
  int node = k*256 + tid;
  if (node < N) rowptr[node] = bstart + excl;
  if (k == nbuck-1 && tid == 0) rowptr[N] = E;
  __syncthreads();
  for (int j = bstart + tid; j < bend; j += 256){
    uint2 s = staged[j];
    int dloc = (int)(s.y & 255);
    int pos = basep[dloc] + atomicAdd(&cur[dloc], 1);
    packed[pos] = s.x;
  }
}

// ---------------- input embedding ----------------
__global__ void embed_kernel(const int* __restrict__ x, const float* __restrict__ xemb,
                             _Float16* __restrict__ h, int N){
  int t = blockIdx.x*256 + threadIdx.x;
  if (t >= N*16) return;
  int n = t >> 4, c = (t & 15) * 8;
  int x0 = x[2*n], x1 = x[2*n+1];
  const float* r0 = xemb + (size_t)x0*D + c;
  const float* r1 = xemb + (size_t)(120 + x1)*D + c;
  half8 o;
  #pragma unroll
  for (int j = 0; j < 8; ++j) o[j] = (_Float16)(r0[j] + r1[j]);
  *(half8*)(h + (size_t)n*D + c) = o;
}

// ---------------- per-layer constant tables ----------------
__global__ void prep_tables(const float* __restrict__ etab, const float* __restrict__ gamma,
                            const float* __restrict__ beta, const float* __restrict__ mean,
                            const float* __restrict__ var, const float* __restrict__ b2,
                            float* __restrict__ comb, float* __restrict__ sc, float* __restrict__ sh){
  int l = blockIdx.x, d = threadIdx.x;
  const float* et = etab + (size_t)l*9*D;
  float* cl = comb + (size_t)l*10*D;
  #pragma unroll
  for (int b = 0; b < 3; ++b)
    #pragma unroll
    for (int dd = 0; dd < 3; ++dd)
      cl[(b*3+dd)*D + d] = et[b*D + d] + et[(6+dd)*D + d];
  cl[9*D + d] = et[4*D + d] + et[6*D + d];
  float A = gamma[l*D+d] * rsqrtf(var[l*D+d] + 1e-5f);
  sc[l*D+d] = A;
  sh[l*D+d] = (b2[l*D+d] - mean[l*D+d]) * A + beta[l*D+d];
}

// repack weights fragment-major for coalesced B loads
__global__ void repack_weights(const float* __restrict__ w1, const float* __restrict__ w2,
                               _Float16* __restrict__ w1f, _Float16* __restrict__ w2f, int total){
  int i = blockIdx.x*256 + threadIdx.x;
  if (i >= total) return;                 // total = 5*H*D
  int l = i / (H*D), r = i % (H*D);
  {
    int n = r / D, k = r % D;
    w1f[(size_t)l*H*D + (size_t)(k>>3)*(H*8) + n*8 + (k&7)] = (_Float16)w1[i];
  }
  {
    int n2 = r / H, k2 = r % H;
    w2f[(size_t)l*D*H + (size_t)(k2>>3)*(D*8) + n2*8 + (k2&7)] = (_Float16)w2[i];
  }
}

// ---------------- aggregation: one wave/node, half-wave dual-row gather ----------------
// Lane covers 4 cols (8 B). Lanes 0-31 gather even edges, 32-63 odd edges:
// 2 edges per VMEM instruction, 16 VMEM per 16 edges (was 32).
__global__ __launch_bounds__(256) void agg_kernel(
    const _Float16* __restrict__ h, const unsigned* __restrict__ packed,
    const int* __restrict__ rowptr, const float* __restrict__ comb,
    _Float16* __restrict__ agg, int N){
  __shared__ float cl[10*D];
  int tid = threadIdx.x;
  for (int i = tid; i < 10*D; i += 256) cl[i] = comb[i];
  __syncthreads();
  int node = __builtin_amdgcn_readfirstlane(blockIdx.x*4 + (tid >> 6)); // wave-uniform
  if (node >= N) return;
  int lane = tid & 63;
  int half = lane >> 5;
  int c = (lane & 31) * 4;
  float a0 = 0.f, a1 = 0.f, a2 = 0.f, a3 = 0.f;
  if (half == 0){
    half4 hv = *(const half4*)(h + (size_t)node*D + c);
    a0 = (float)hv[0] + cl[9*D + c];
    a1 = (float)hv[1] + cl[9*D + c + 1];
    a2 = (float)hv[2] + cl[9*D + c + 2];
    a3 = (float)hv[3] + cl[9*D + c + 3];
  }
  int beg = rowptr[node], end = rowptr[node+1];
  unsigned long long cp = 0;   // 9 codes x 7-bit counters
  for (int j = beg; j < end; j += 16){
    int m = end - j;                     // wave-uniform remaining
    uint2 q[8];
    #pragma unroll
    for (int k = 0; k < 8; ++k) if (2*k < m) q[k] = *(const uint2*)(packed + j + 2*k);
    half4 v[8];
    #pragma unroll
    for (int k = 0; k < 8; ++k){
      int idx = 2*k + half;
      if (idx < m){
        unsigned pw = half ? q[k].y : q[k].x;
        v[k] = *(const half4*)(h + (size_t)(pw & 0xFFFFFu)*D + c);
      }
    }
    #pragma unroll
    for (int k = 0; k < 8; ++k){
      int idx = 2*k + half;
      if (idx < m){
        unsigned pw = half ? q[k].y : q[k].x;
        cp += 1ULL << (7*(int)(pw >> 20));
        a0 += (float)v[k][0];
        a1 += (float)v[k][1];
        a2 += (float)v[k][2];
        a3 += (float)v[k][3];
      }
    }
  }
  // combine the two half-waves (columns identical, edge subsets disjoint)
  {
    unsigned lo = (unsigned)cp, hi = (unsigned)(cp >> 32);
    unsigned olo = __shfl_xor(lo, 32, 64);
    unsigned ohi = __shfl_xor(hi, 32, 64);
    cp += ((unsigned long long)ohi << 32) | olo;
  }
  a0 += __shfl_xor(a0, 32, 64);
  a1 += __shfl_xor(a1, 32, 64);
  a2 += __shfl_xor(a2, 32, 64);
  a3 += __shfl_xor(a3, 32, 64);
  #pragma unroll
  for (int cd = 0; cd < 9; ++cd){
    float cnt = (float)(int)((cp >> (7*cd)) & 127);
    a0 += cnt * cl[cd*D + c];
    a1 += cnt * cl[cd*D + c + 1];
    a2 += cnt * cl[cd*D + c + 2];
    a3 += cnt * cl[cd*D + c + 3];
  }
  if (half == 0){
    half4 o;
    o[0] = (_Float16)a0; o[1] = (_Float16)a1; o[2] = (_Float16)a2; o[3] = (_Float16)a3;
    *(half4*)(agg + (size_t)node*D + c) = o;
  }
}

// ---------------- fused GIN MLP: stage A->LDS(swizzled), GEMM1+ReLU -> GEMM2+BN --------
__global__ __launch_bounds__(256) void mlp_kernel(
    const _Float16* __restrict__ agg, const _Float16* __restrict__ w1f,
    const _Float16* __restrict__ w2f, const float* __restrict__ b1,
    const float* __restrict__ sc, const float* __restrict__ sh,
    _Float16* __restrict__ hout, float* __restrict__ fout,
    int N, int relu_out){
  __shared__ __align__(16) char smem[64*256*2];
  _Float16* atile = (_Float16*)smem;   // row*128 + (c8 ^ (row&15))*8 + (col&7)
  _Float16* hmid  = (_Float16*)smem;   // row*256 + (c8 ^ (row&31))*8 + (col&7)
  int tid = threadIdx.x;
  int wave = tid >> 6, lane = tid & 63;
  int quad = lane >> 4, l15 = lane & 15;
  int r0 = blockIdx.x * 64;

  half8 zf;
  #pragma unroll
  for (int j = 0; j < 8; ++j) zf[j] = (_Float16)0.f;

  #pragma unroll
  for (int i = 0; i < 4; ++i){
    int ci = i*256 + tid;
    int row = ci >> 4, c8 = ci & 15;
    int m = r0 + row;
    half8 v = (m < N) ? *(const half8*)(agg + (size_t)m*D + c8*8) : zf;
    *(half8*)(atile + row*128 + ((c8 ^ (row & 15)) * 8)) = v;
  }
  __syncthreads();

  floatx4 acc[4][4] = {};
  half8 bcur[4], bnxt[4];
  #pragma unroll
  for (int nt = 0; nt < 4; ++nt)
    bcur[nt] = *(const half8*)(w1f + (size_t)quad*(H*8) + (wave*64 + nt*16 + l15)*8);
  #pragma unroll
  for (int ks = 0; ks < 4; ++ks){
    if (ks < 3){
      #pragma unroll
      for (int nt = 0; nt < 4; ++nt)
        bnxt[nt] = *(const half8*)(w1f + (size_t)((ks+1)*4 + quad)*(H*8) + (wave*64 + nt*16 + l15)*8);
    }
    int c8 = ks*4 + quad;
    half8 af[4];
    #pragma unroll
    for (int mt = 0; mt < 4; ++mt)
      af[mt] = *(const half8*)(atile + (mt*16 + l15)*128 + ((c8 ^ l15) * 8));
    #pragma unroll
    for (int mt = 0; mt < 4; ++mt)
      #pragma unroll
      for (int nt = 0; nt < 4; ++nt)
        acc[mt][nt] = __builtin_amdgcn_mfma_f32_16x16x32_f16(af[mt], bcur[nt], acc[mt][nt], 0, 0, 0);
    #pragma unroll
    for (int nt = 0; nt < 4; ++nt) bcur[nt] = bnxt[nt];
  }
  __syncthreads();

  #pragma unroll
  for (int nt = 0; nt < 4; ++nt){
    int n = wave*64 + nt*16 + l15;
    float bias = b1[n];
    #pragma unroll
    for (int mt = 0; mt < 4; ++mt)
      #pragma unroll
      for (int r = 0; r < 4; ++r){
        int row = mt*16 + quad*4 + r;
        hmid[row*256 + (((n >> 3) ^ (row & 31)) * 8) + (n & 7)] =
            (_Float16)fmaxf(acc[mt][nt][r] + bias, 0.f);
      }
  }
  __syncthreads();

  floatx4 acc2[4][2] = {};
  half8 gcur[2], gnxt[2];
  #pragma unroll
  for (int nt = 0; nt < 2; ++nt)
    gcur[nt] = *(const half8*)(w2f + (size_t)quad*(D*8) + (wave*32 + nt*16 + l15)*8);
  #pragma unroll
  for (int ks = 0; ks < 8; ++ks){
    if (ks < 7){
      #pragma unroll
      for (int nt = 0; nt < 2; ++nt)
        gnxt[nt] = *(const half8*)(w2f + (size_t)((ks+1)*4 + quad)*(D*8) + (wave*32 + nt*16 + l15)*8);
    }
    int c8 = ks*4 + quad;
    half8 af[4];
    #pragma unroll
    for (int mt = 0; mt < 4; ++mt){
      int row = mt*16 + l15;
      af[mt] = *(const half8*)(hmid + row*256 + ((c8 ^ (row & 31)) * 8));
    }
    #pragma unroll
    for (int mt = 0; mt < 4; ++mt)
      #pragma unroll
      for (int nt = 0; nt < 2; ++nt)
        acc2[mt][nt] = __builtin_amdgcn_mfma_f32_16x16x32_f16(af[mt], gcur[nt], acc2[mt][nt], 0, 0, 0);
    #pragma unroll
    for (int nt = 0; nt < 2; ++nt) gcur[nt] = gnxt[nt];
  }

  #pragma unroll
  for (int nt = 0; nt < 2; ++nt){
    int n = wave*32 + nt*16 + l15;
    float A = sc[n], B = sh[n];
    #pragma unroll
    for (int mt = 0; mt < 4; ++mt)
      #pragma unroll
      for (int r = 0; r < 4; ++r){
        int row = r0 + mt*16 + quad*4 + r;
        if (row < N){
          float v = acc2[mt][nt][r]*A + B;
          if (relu_out) v = fmaxf(v, 0.f);
          if (fout) fout[(size_t)row*D + n] = v;
          else      hout[(size_t)row*D + n] = (_Float16)v;
        }
      }
  }
}

extern "C" void kernel_launch(void* const* d_in, const int* in_sizes, int n_in,
                              void* d_out, int out_size, void* d_ws, size_t ws_size,
                              hipStream_t stream){
  const int*   x     = (const int*)d_in[0];
  const int*   ei    = (const int*)d_in[1];
  const int*   ea    = (const int*)d_in[2];
  const float* xemb  = (const float*)d_in[3];
  const float* etab  = (const float*)d_in[4];
  const float* w1    = (const float*)d_in[5];
  const float* b1    = (const float*)d_in[6];
  const float* w2    = (const float*)d_in[7];
  const float* b2    = (const float*)d_in[8];
  const float* gamma = (const float*)d_in[9];
  const float* beta  = (const float*)d_in[10];
  const float* mean  = (const float*)d_in[11];
  const float* var   = (const float*)d_in[12];
  float* out = (float*)d_out;

  int N = in_sizes[0] / 2;
  int E = in_sizes[1] / 2;
  int nbuck = (N + 255) >> 8;              // 391 buckets (must be <= 512)
  int M = nbuck * NBLK;                    // (bucket, block) counter matrix
  int nbM = (M + 1023) / 1024;             // scan blocks for M
  int chunk = (E + NBLK - 1) / NBLK;

  char* ws = (char*)d_ws;
  size_t off = 0;
  auto alloc = [&](size_t b){ void* p = ws + off; off += (b + 255) & ~(size_t)255; return p; };
  _Float16* h      = (_Float16*)alloc((size_t)N*D*2);
  _Float16* agg    = (_Float16*)alloc((size_t)N*D*2);    // staged aliases this (E*8 <= N*D*2)
  unsigned* packed = (unsigned*)alloc((size_t)(E+16)*4);
  int*      rowptr = (int*)alloc((size_t)(N+1)*4);
  int*      cntBB  = (int*)alloc((size_t)M*4);
  int*      baseBB = (int*)alloc((size_t)(M+1)*4);
  int*      bsum   = (int*)alloc((size_t)nbM*4);
  int*      bbase  = (int*)alloc((size_t)nbM*4);
  _Float16* w1f    = (_Float16*)alloc((size_t)5*H*D*2);
  _Float16* w2f    = (_Float16*)alloc((size_t)5*D*H*2);
  float*    comb   = (float*)alloc((size_t)5*10*D*4);
  float*    sc     = (float*)alloc((size_t)5*D*4);
  float*    sh     = (float*)alloc((size_t)5*D*4);
  uint2*    staged = (uint2*)agg;   // dead before agg_kernel first writes agg

  const int* srcp = ei;
  const int* dstp = ei + E;

  part_count<<<NBLK, 256, 0, stream>>>(dstp, cntBB, E, chunk, nbuck);
  scan_part <<<nbM, 256, 0, stream>>>(cntBB, bsum, M);
  scan_bsums<<<1, 1024, 0, stream>>>(bsum, bbase, baseBB, nbM, M);   // baseBB[M] = E
  scan_emit <<<nbM, 256, 0, stream>>>(cntBB, bbase, baseBB, M);
  part_bin  <<<NBLK, 256, 0, stream>>>(srcp, dstp, ea, baseBB, staged, E, chunk, nbuck);
  part_emit <<<nbuck, 256, 0, stream>>>(staged, baseBB, packed, rowptr, N, E, nbuck, M);
  repack_weights<<<(5*H*D+255)/256, 256, 0, stream>>>(w1, w2, w1f, w2f, 5*H*D);
  prep_tables<<<5, 128, 0, stream>>>(etab, gamma, beta, mean, var, b2, comb, sc, sh);
  embed_kernel<<<((size_t)N*16+255)/256, 256, 0, stream>>>(x, xemb, h, N);

  for (int l = 0; l < 5; ++l){
    agg_kernel<<<(N+3)/4, 256, 0, stream>>>(h, packed, rowptr, comb + (size_t)l*10*D, agg, N);
    int last = (l == 4);
    mlp_kernel<<<(N+63)/64, 256, 0, stream>>>(agg, w1f + (size_t)l*H*D, w2f + (size_t)l*D*H,
        b1 + (size_t)l*H, sc + (size_t)l*D, sh + (size_t)l*D,
        last ? (_Float16*)nullptr : h, last ? out : (float*)nullptr,
        N, last ? 0 : 1);
  }
}

// Round 7
// 955.188 us; speedup vs baseline: 1.2413x; 1.2413x over previous
//
#include <hip/hip_runtime.h>

#define D 128
#define H 256
#define NBLK 512          // partition blocks
#define BUCKSH 8          // bucket = dst >> 8  (256 nodes/bucket)

typedef _Float16 half8 __attribute__((ext_vector_type(8)));
typedef _Float16 half2v __attribute__((ext_vector_type(2)));
typedef float floatx4 __attribute__((ext_vector_type(4)));
typedef float float2v __attribute__((ext_vector_type(2)));

// ======== multi-block exclusive scan ========
__global__ __launch_bounds__(256) void scan_part(const int* __restrict__ cnt,
                                                 int* __restrict__ bsum, int N){
  int base = blockIdx.x*1024;
  int tid = threadIdx.x;
  int idx = base + tid*4;
  int4 v = {0,0,0,0};
  if (idx + 3 < N) v = *(const int4*)(cnt + idx);
  else {
    if (idx   < N) v.x = cnt[idx];
    if (idx+1 < N) v.y = cnt[idx+1];
    if (idx+2 < N) v.z = cnt[idx+2];
    if (idx+3 < N) v.w = cnt[idx+3];
  }
  int s = v.x + v.y + v.z + v.w;
  #pragma unroll
  for (int off = 32; off > 0; off >>= 1) s += __shfl_down(s, off, 64);
  __shared__ int ws[4];
  int lane = tid & 63, wave = tid >> 6;
  if (lane == 0) ws[wave] = s;
  __syncthreads();
  if (tid == 0) bsum[blockIdx.x] = ws[0] + ws[1] + ws[2] + ws[3];
}

__global__ __launch_bounds__(1024) void scan_bsums(const int* __restrict__ bsum,
                                                   int* __restrict__ bbase,
                                                   int* __restrict__ total_out, int nb, int N){
  __shared__ int sh[1024];
  int tid = threadIdx.x;
  int v = (tid < nb) ? bsum[tid] : 0;
  sh[tid] = v;
  __syncthreads();
  #pragma unroll
  for (int off = 1; off < 1024; off <<= 1){
    int t = 0;
    if (tid >= off) t = sh[tid - off];
    __syncthreads();
    if (tid >= off) sh[tid] += t;
    __syncthreads();
  }
  if (tid < nb) bbase[tid] = sh[tid] - v;
  if (tid == 0) total_out[N] = sh[1023];   // grand total at [N]
}

__global__ __launch_bounds__(256) void scan_emit(const int* __restrict__ cnt,
                                                 const int* __restrict__ bbase,
                                                 int* __restrict__ outp, int N){
  int base = blockIdx.x*1024;
  int tid = threadIdx.x;
  int idx = base + tid*4;
  int4 v = {0,0,0,0};
  if (idx + 3 < N) v = *(const int4*)(cnt + idx);
  else {
    if (idx   < N) v.x = cnt[idx];
    if (idx+1 < N) v.y = cnt[idx+1];
    if (idx+2 < N) v.z = cnt[idx+2];
    if (idx+3 < N) v.w = cnt[idx+3];
  }
  int s = v.x + v.y + v.z + v.w;
  int lane = tid & 63, wave = tid >> 6;
  int incl = s;
  #pragma unroll
  for (int off = 1; off < 64; off <<= 1){
    int t = __shfl_up(incl, off, 64);
    if (lane >= off) incl += t;
  }
  __shared__ int ws[4];
  if (lane == 63) ws[wave] = incl;
  __syncthreads();
  int woff = 0;
  #pragma unroll
  for (int w = 0; w < 4; ++w) if (w < wave) woff += ws[w];
  int off0 = bbase[blockIdx.x] + woff + (incl - s);
  if (idx   < N) outp[idx]   = off0;
  if (idx+1 < N) outp[idx+1] = off0 + v.x;
  if (idx+2 < N) outp[idx+2] = off0 + v.x + v.y;
  if (idx+3 < N) outp[idx+3] = off0 + v.x + v.y + v.z;
}

// ======== 3-pass CSR partition build ========
__global__ __launch_bounds__(256) void part_count(const int* __restrict__ dst,
                                                  int* __restrict__ cntBB,
                                                  int E, int chunk, int nbuck){
  __shared__ int lc[512];
  int b = blockIdx.x;
  for (int i = threadIdx.x; i < nbuck; i += 256) lc[i] = 0;
  __syncthreads();
  int e0 = b*chunk, e1 = min(e0 + chunk, E);
  for (int e = e0 + threadIdx.x; e < e1; e += 256)
    atomicAdd(&lc[dst[e] >> BUCKSH], 1);
  __syncthreads();
  for (int i = threadIdx.x; i < nbuck; i += 256) cntBB[i*NBLK + b] = lc[i];
}

__global__ __launch_bounds__(256) void part_bin(const int* __restrict__ src,
                                                const int* __restrict__ dst,
                                                const int* __restrict__ ea,
                                                const int* __restrict__ baseBB,
                                                uint2* __restrict__ staged,
                                                int E, int chunk, int nbuck){
  __shared__ int run[512];
  int b = blockIdx.x;
  for (int i = threadIdx.x; i < nbuck; i += 256) run[i] = baseBB[i*NBLK + b];
  __syncthreads();
  int e0 = b*chunk, e1 = min(e0 + chunk, E);
  for (int e = e0 + threadIdx.x; e < e1; e += 256){
    int d = dst[e];
    unsigned pv = ((unsigned)(ea[2*e]*3 + ea[2*e+1]) << 20) | (unsigned)src[e];
    int pos = atomicAdd(&run[d >> BUCKSH], 1);
    uint2 s; s.x = pv; s.y = (unsigned)d;
    staged[pos] = s;
  }
}

__global__ __launch_bounds__(256) void part_emit(const uint2* __restrict__ staged,
                                                 const int* __restrict__ baseBB,
                                                 unsigned* __restrict__ packed,
                                                 int* __restrict__ rowptr,
                                                 int N, int E, int nbuck, int M){
  __shared__ int ncnt[256];
  __shared__ int sscan[256];
  __shared__ int basep[256];
  __shared__ int cur[256];
  int k = blockIdx.x;
  int tid = threadIdx.x;
  int bstart = baseBB[k*NBLK];
  int bend = (k+1 < nbuck) ? baseBB[(k+1)*NBLK] : baseBB[M];
  ncnt[tid] = 0; cur[tid] = 0;
  __syncthreads();
  for (int j = bstart + tid; j < bend; j += 256)
    atomicAdd(&ncnt[staged[j].y & 255], 1);
  __syncthreads();
  int v = ncnt[tid];
  sscan[tid] = v;
  __syncthreads();
  #pragma unroll
  for (int off = 1; off < 256; off <<= 1){
    int t = (tid >= off) ? sscan[tid-off] : 0;
    __syncthreads();
    sscan[tid] += t;
    __syncthreads();
  }
  int excl = sscan[tid] - v;
  basep[tid] = bstart + excl;
  int node = k*256 + tid;
  if (node < N) rowptr[node] = bstart + excl;
  if (k == nbuck-1 && tid == 0) rowptr[N] = E;
  __syncthreads();
  for (int j = bstart + tid; j < bend; j += 256){
    uint2 s = staged[j];
    int dloc = (int)(s.y & 255);
    int pos = basep[dloc] + atomicAdd(&cur[dloc], 1);
    packed[pos] = s.x;
  }
}

// ---------------- input embedding -> fp8 h ----------------
__global__ void embed_kernel(const int* __restrict__ x, const float* __restrict__ xemb,
                             unsigned char* __restrict__ h, int N){
  int t = blockIdx.x*256 + threadIdx.x;
  if (t >= N*32) return;
  int n = t >> 5, c = (t & 31) * 4;
  int x0 = x[2*n], x1 = x[2*n+1];
  const float* r0 = xemb + (size_t)x0*D + c;
  const float* r1 = xemb + (size_t)(120 + x1)*D + c;
  float a0 = r0[0] + r1[0], a1 = r0[1] + r1[1];
  float a2 = r0[2] + r1[2], a3 = r0[3] + r1[3];
  int p0 = __builtin_amdgcn_cvt_pk_fp8_f32(a0, a1, 0, false);
  int p1 = __builtin_amdgcn_cvt_pk_fp8_f32(a2, a3, p0, true);
  *(unsigned*)(h + (size_t)n*D + c) = (unsigned)p1;
}

// ---------------- per-layer constant tables ----------------
__global__ void prep_tables(const float* __restrict__ etab, const float* __restrict__ gamma,
                            const float* __restrict__ beta, const float* __restrict__ mean,
                            const float* __restrict__ var, const float* __restrict__ b2,
                            float* __restrict__ comb, float* __restrict__ sc, float* __restrict__ sh){
  int l = blockIdx.x, d = threadIdx.x;
  const float* et = etab + (size_t)l*9*D;
  float* cl = comb + (size_t)l*10*D;
  #pragma unroll
  for (int b = 0; b < 3; ++b)
    #pragma unroll
    for (int dd = 0; dd < 3; ++dd)
      cl[(b*3+dd)*D + d] = et[b*D + d] + et[(6+dd)*D + d];
  cl[9*D + d] = et[4*D + d] + et[6*D + d];
  float A = gamma[l*D+d] * rsqrtf(var[l*D+d] + 1e-5f);
  sc[l*D+d] = A;
  sh[l*D+d] = (b2[l*D+d] - mean[l*D+d]) * A + beta[l*D+d];
}

// repack weights fragment-major for coalesced B loads
__global__ void repack_weights(const float* __restrict__ w1, const float* __restrict__ w2,
                               _Float16* __restrict__ w1f, _Float16* __restrict__ w2f, int total){
  int i = blockIdx.x*256 + threadIdx.x;
  if (i >= total) return;                 // total = 5*H*D
  int l = i / (H*D), r = i % (H*D);
  {
    int n = r / D, k = r % D;
    w1f[(size_t)l*H*D + (size_t)(k>>3)*(H*8) + n*8 + (k&7)] = (_Float16)w1[i];
  }
  {
    int n2 = r / H, k2 = r % H;
    w2f[(size_t)l*D*H + (size_t)(k2>>3)*(D*8) + n2*8 + (k2&7)] = (_Float16)w2[i];
  }
}

// ---------------- aggregation: one wave per node, fp8 gather (128 B/row) ----------------
__global__ __launch_bounds__(256) void agg_kernel(
    const unsigned char* __restrict__ h, const unsigned* __restrict__ packed,
    const int* __restrict__ rowptr, const float* __restrict__ comb,
    _Float16* __restrict__ agg, int N){
  __shared__ float cl[10*D];
  int tid = threadIdx.x;
  for (int i = tid; i < 10*D; i += 256) cl[i] = comb[i];
  __syncthreads();
  int node = __builtin_amdgcn_readfirstlane(blockIdx.x*4 + (tid >> 6)); // wave-uniform
  if (node >= N) return;
  int lane = tid & 63;
  int c = lane * 2;                      // 2 fp8 values per lane
  unsigned sv = *(const unsigned short*)(h + (size_t)node*D + c);
  float2v sf = __builtin_amdgcn_cvt_pk_f32_fp8((int)sv, false);
  float ax = sf.x + cl[9*D + c];
  float ay = sf.y + cl[9*D + c + 1];
  int beg = rowptr[node], end = rowptr[node+1];
  unsigned long long cp = 0;             // 9 codes x 7-bit counters
  for (int j = beg; j < end; j += 8){
    int m = end - j;                     // wave-uniform
    unsigned p[8];
    #pragma unroll
    for (int k = 0; k < 8; ++k) if (k < m) p[k] = packed[j+k];
    unsigned short v[8];
    #pragma unroll
    for (int k = 0; k < 8; ++k) if (k < m)
      v[k] = *(const unsigned short*)(h + (size_t)(p[k] & 0xFFFFFu)*D + c);
    #pragma unroll
    for (int k = 0; k < 8; ++k) if (k < m){
      cp += 1ULL << (7*(int)(p[k] >> 20));
      float2v f = __builtin_amdgcn_cvt_pk_f32_fp8((int)v[k], false);
      ax += f.x;
      ay += f.y;
    }
  }
  #pragma unroll
  for (int cd = 0; cd < 9; ++cd){
    float cnt = (float)(int)((cp >> (7*cd)) & 127);
    ax += cnt * cl[cd*D + c];
    ay += cnt * cl[cd*D + c + 1];
  }
  half2v o; o.x = (_Float16)ax; o.y = (_Float16)ay;
  *(half2v*)(agg + (size_t)node*D + c) = o;
}

// ---------------- fused GIN MLP: stage A->LDS(swizzled), GEMM1+ReLU -> GEMM2+BN --------
__global__ __launch_bounds__(256) void mlp_kernel(
    const _Float16* __restrict__ agg, const _Float16* __restrict__ w1f,
    const _Float16* __restrict__ w2f, const float* __restrict__ b1,
    const float* __restrict__ sc, const float* __restrict__ sh,
    unsigned char* __restrict__ hout, float* __restrict__ fout,
    int N, int relu_out){
  __shared__ __align__(16) char smem[64*256*2];
  _Float16* atile = (_Float16*)smem;   // row*128 + (c8 ^ (row&15))*8 + (col&7)
  _Float16* hmid  = (_Float16*)smem;   // row*256 + (c8 ^ (row&31))*8 + (col&7)
  int tid = threadIdx.x;
  int wave = tid >> 6, lane = tid & 63;
  int quad = lane >> 4, l15 = lane & 15;
  int r0 = blockIdx.x * 64;

  half8 zf;
  #pragma unroll
  for (int j = 0; j < 8; ++j) zf[j] = (_Float16)0.f;

  #pragma unroll
  for (int i = 0; i < 4; ++i){
    int ci = i*256 + tid;
    int row = ci >> 4, c8 = ci & 15;
    int m = r0 + row;
    half8 v = (m < N) ? *(const half8*)(agg + (size_t)m*D + c8*8) : zf;
    *(half8*)(atile + row*128 + ((c8 ^ (row & 15)) * 8)) = v;
  }
  __syncthreads();

  floatx4 acc[4][4] = {};
  half8 bcur[4], bnxt[4];
  #pragma unroll
  for (int nt = 0; nt < 4; ++nt)
    bcur[nt] = *(const half8*)(w1f + (size_t)quad*(H*8) + (wave*64 + nt*16 + l15)*8);
  #pragma unroll
  for (int ks = 0; ks < 4; ++ks){
    if (ks < 3){
      #pragma unroll
      for (int nt = 0; nt < 4; ++nt)
        bnxt[nt] = *(const half8*)(w1f + (size_t)((ks+1)*4 + quad)*(H*8) + (wave*64 + nt*16 + l15)*8);
    }
    int c8 = ks*4 + quad;
    half8 af[4];
    #pragma unroll
    for (int mt = 0; mt < 4; ++mt)
      af[mt] = *(const half8*)(atile + (mt*16 + l15)*128 + ((c8 ^ l15) * 8));
    #pragma unroll
    for (int mt = 0; mt < 4; ++mt)
      #pragma unroll
      for (int nt = 0; nt < 4; ++nt)
        acc[mt][nt] = __builtin_amdgcn_mfma_f32_16x16x32_f16(af[mt], bcur[nt], acc[mt][nt], 0, 0, 0);
    #pragma unroll
    for (int nt = 0; nt < 4; ++nt) bcur[nt] = bnxt[nt];
  }
  __syncthreads();

  #pragma unroll
  for (int nt = 0; nt < 4; ++nt){
    int n = wave*64 + nt*16 + l15;
    float bias = b1[n];
    #pragma unroll
    for (int mt = 0; mt < 4; ++mt)
      #pragma unroll
      for (int r = 0; r < 4; ++r){
        int row = mt*16 + quad*4 + r;
        hmid[row*256 + (((n >> 3) ^ (row & 31)) * 8) + (n & 7)] =
            (_Float16)fmaxf(acc[mt][nt][r] + bias, 0.f);
      }
  }
  __syncthreads();

  floatx4 acc2[4][2] = {};
  half8 gcur[2], gnxt[2];
  #pragma unroll
  for (int nt = 0; nt < 2; ++nt)
    gcur[nt] = *(const half8*)(w2f + (size_t)quad*(D*8) + (wave*32 + nt*16 + l15)*8);
  #pragma unroll
  for (int ks = 0; ks < 8; ++ks){
    if (ks < 7){
      #pragma unroll
      for (int nt = 0; nt < 2; ++nt)
        gnxt[nt] = *(const half8*)(w2f + (size_t)((ks+1)*4 + quad)*(D*8) + (wave*32 + nt*16 + l15)*8);
    }
    int c8 = ks*4 + quad;
    half8 af[4];
    #pragma unroll
    for (int mt = 0; mt < 4; ++mt){
      int row = mt*16 + l15;
      af[mt] = *(const half8*)(hmid + row*256 + ((c8 ^ (row & 31)) * 8));
    }
    #pragma unroll
    for (int mt = 0; mt < 4; ++mt)
      #pragma unroll
      for (int nt = 0; nt < 2; ++nt)
        acc2[mt][nt] = __builtin_amdgcn_mfma_f32_16x16x32_f16(af[mt], gcur[nt], acc2[mt][nt], 0, 0, 0);
    #pragma unroll
    for (int nt = 0; nt < 2; ++nt) gcur[nt] = gnxt[nt];
  }

  #pragma unroll
  for (int nt = 0; nt < 2; ++nt){
    int n = wave*32 + nt*16 + l15;
    float A = sc[n], B = sh[n];
    #pragma unroll
    for (int mt = 0; mt < 4; ++mt)
      #pragma unroll
      for (int r = 0; r < 4; ++r){
        int row = r0 + mt*16 + quad*4 + r;
        if (row < N){
          float v = acc2[mt][nt][r]*A + B;
          if (fout) fout[(size_t)row*D + n] = v;
          else {
            v = fmaxf(v, 0.f);            // relu_out is 1 whenever hout path used
            int pb = __builtin_amdgcn_cvt_pk_fp8_f32(v, v, 0, false);
            hout[(size_t)row*D + n] = (unsigned char)(pb & 0xFF);
          }
        }
      }
  }
}

extern "C" void kernel_launch(void* const* d_in, const int* in_sizes, int n_in,
                              void* d_out, int out_size, void* d_ws, size_t ws_size,
                              hipStream_t stream){
  const int*   x     = (const int*)d_in[0];
  const int*   ei    = (const int*)d_in[1];
  const int*   ea    = (const int*)d_in[2];
  const float* xemb  = (const float*)d_in[3];
  const float* etab  = (const float*)d_in[4];
  const float* w1    = (const float*)d_in[5];
  const float* b1    = (const float*)d_in[6];
  const float* w2    = (const float*)d_in[7];
  const float* b2    = (const float*)d_in[8];
  const float* gamma = (const float*)d_in[9];
  const float* beta  = (const float*)d_in[10];
  const float* mean  = (const float*)d_in[11];
  const float* var   = (const float*)d_in[12];
  float* out = (float*)d_out;

  int N = in_sizes[0] / 2;
  int E = in_sizes[1] / 2;
  int nbuck = (N + 255) >> 8;
  int M = nbuck * NBLK;
  int nbM = (M + 1023) / 1024;
  int chunk = (E + NBLK - 1) / NBLK;

  char* ws = (char*)d_ws;
  size_t off = 0;
  auto alloc = [&](size_t b){ void* p = ws + off; off += (b + 255) & ~(size_t)255; return p; };
  unsigned char* h = (unsigned char*)alloc((size_t)N*D);
  _Float16* agg    = (_Float16*)alloc((size_t)N*D*2);    // staged aliases this (E*8 <= N*D*2)
  unsigned* packed = (unsigned*)alloc((size_t)(E+16)*4);
  int*      rowptr = (int*)alloc((size_t)(N+1)*4);
  int*      cntBB  = (int*)alloc((size_t)M*4);
  int*      baseBB = (int*)alloc((size_t)(M+1)*4);
  int*      bsum   = (int*)alloc((size_t)nbM*4);
  int*      bbase  = (int*)alloc((size_t)nbM*4);
  _Float16* w1f    = (_Float16*)alloc((size_t)5*H*D*2);
  _Float16* w2f    = (_Float16*)alloc((size_t)5*D*H*2);
  float*    comb   = (float*)alloc((size_t)5*10*D*4);
  float*    sc     = (float*)alloc((size_t)5*D*4);
  float*    sh     = (float*)alloc((size_t)5*D*4);
  uint2*    staged = (uint2*)agg;   // dead before agg_kernel first writes agg

  const int* srcp = ei;
  const int* dstp = ei + E;

  part_count<<<NBLK, 256, 0, stream>>>(dstp, cntBB, E, chunk, nbuck);
  scan_part <<<nbM, 256, 0, stream>>>(cntBB, bsum, M);
  scan_bsums<<<1, 1024, 0, stream>>>(bsum, bbase, baseBB, nbM, M);   // baseBB[M] = E
  scan_emit <<<nbM, 256, 0, stream>>>(cntBB, bbase, baseBB, M);
  part_bin  <<<NBLK, 256, 0, stream>>>(srcp, dstp, ea, baseBB, staged, E, chunk, nbuck);
  part_emit <<<nbuck, 256, 0, stream>>>(staged, baseBB, packed, rowptr, N, E, nbuck, M);
  repack_weights<<<(5*H*D+255)/256, 256, 0, stream>>>(w1, w2, w1f, w2f, 5*H*D);
  prep_tables<<<5, 128, 0, stream>>>(etab, gamma, beta, mean, var, b2, comb, sc, sh);
  embed_kernel<<<((size_t)N*32+255)/256, 256, 0, stream>>>(x, xemb, h, N);

  for (int l = 0; l < 5; ++l){
    agg_kernel<<<(N+3)/4, 256, 0, stream>>>(h, packed, rowptr, comb + (size_t)l*10*D, agg, N);
    int last = (l == 4);
    mlp_kernel<<<(N+63)/64, 256, 0, stream>>>(agg, w1f + (size_t)l*H*D, w2f + (size_t)l*D*H,
        b1 + (size_t)l*H, sc + (size_t)l*D, sh + (size_t)l*D,
        last ? (unsigned char*)nullptr : h, last ? out : (float*)nullptr,
        N, last ? 0 : 1);
  }
}

// Round 8
// 764.157 us; speedup vs baseline: 1.5516x; 1.2500x over previous
//
#include <hip/hip_runtime.h>

#define D 128
#define H 256
#define NBLK 512          // partition blocks
#define BUCKSH 8          // bucket = dst >> 8  (256 nodes/bucket)

typedef _Float16 half8 __attribute__((ext_vector_type(8)));
typedef _Float16 half2v __attribute__((ext_vector_type(2)));
typedef float floatx4 __attribute__((ext_vector_type(4)));

// ======== multi-block exclusive scan ========
__global__ __launch_bounds__(256) void scan_part(const int* __restrict__ cnt,
                                                 int* __restrict__ bsum, int N){
  int base = blockIdx.x*1024;
  int tid = threadIdx.x;
  int idx = base + tid*4;
  int4 v = {0,0,0,0};
  if (idx + 3 < N) v = *(const int4*)(cnt + idx);
  else {
    if (idx   < N) v.x = cnt[idx];
    if (idx+1 < N) v.y = cnt[idx+1];
    if (idx+2 < N) v.z = cnt[idx+2];
    if (idx+3 < N) v.w = cnt[idx+3];
  }
  int s = v.x + v.y + v.z + v.w;
  #pragma unroll
  for (int off = 32; off > 0; off >>= 1) s += __shfl_down(s, off, 64);
  __shared__ int ws[4];
  int lane = tid & 63, wave = tid >> 6;
  if (lane == 0) ws[wave] = s;
  __syncthreads();
  if (tid == 0) bsum[blockIdx.x] = ws[0] + ws[1] + ws[2] + ws[3];
}

__global__ __launch_bounds__(1024) void scan_bsums(const int* __restrict__ bsum,
                                                   int* __restrict__ bbase,
                                                   int* __restrict__ total_out, int nb, int N){
  __shared__ int sh[1024];
  int tid = threadIdx.x;
  int v = (tid < nb) ? bsum[tid] : 0;
  sh[tid] = v;
  __syncthreads();
  #pragma unroll
  for (int off = 1; off < 1024; off <<= 1){
    int t = 0;
    if (tid >= off) t = sh[tid - off];
    __syncthreads();
    if (tid >= off) sh[tid] += t;
    __syncthreads();
  }
  if (tid < nb) bbase[tid] = sh[tid] - v;
  if (tid == 0) total_out[N] = sh[1023];   // grand total at [N]
}

__global__ __launch_bounds__(256) void scan_emit(const int* __restrict__ cnt,
                                                 const int* __restrict__ bbase,
                                                 int* __restrict__ outp, int N){
  int base = blockIdx.x*1024;
  int tid = threadIdx.x;
  int idx = base + tid*4;
  int4 v = {0,0,0,0};
  if (idx + 3 < N) v = *(const int4*)(cnt + idx);
  else {
    if (idx   < N) v.x = cnt[idx];
    if (idx+1 < N) v.y = cnt[idx+1];
    if (idx+2 < N) v.z = cnt[idx+2];
    if (idx+3 < N) v.w = cnt[idx+3];
  }
  int s = v.x + v.y + v.z + v.w;
  int lane = tid & 63, wave = tid >> 6;
  int incl = s;
  #pragma unroll
  for (int off = 1; off < 64; off <<= 1){
    int t = __shfl_up(incl, off, 64);
    if (lane >= off) incl += t;
  }
  __shared__ int ws[4];
  if (lane == 63) ws[wave] = incl;
  __syncthreads();
  int woff = 0;
  #pragma unroll
  for (int w = 0; w < 4; ++w) if (w < wave) woff += ws[w];
  int off0 = bbase[blockIdx.x] + woff + (incl - s);
  if (idx   < N) outp[idx]   = off0;
  if (idx+1 < N) outp[idx+1] = off0 + v.x;
  if (idx+2 < N) outp[idx+2] = off0 + v.x + v.y;
  if (idx+3 < N) outp[idx+3] = off0 + v.x + v.y + v.z;
}

// ======== 3-pass CSR partition build ========
__global__ __launch_bounds__(256) void part_count(const int* __restrict__ dst,
                                                  int* __restrict__ cntBB,
                                                  int E, int chunk, int nbuck){
  __shared__ int lc[512];
  int b = blockIdx.x;
  for (int i = threadIdx.x; i < nbuck; i += 256) lc[i] = 0;
  __syncthreads();
  int e0 = b*chunk, e1 = min(e0 + chunk, E);
  for (int e = e0 + threadIdx.x; e < e1; e += 256)
    atomicAdd(&lc[dst[e] >> BUCKSH], 1);
  __syncthreads();
  for (int i = threadIdx.x; i < nbuck; i += 256) cntBB[i*NBLK + b] = lc[i];
}

__global__ __launch_bounds__(256) void part_bin(const int* __restrict__ src,
                                                const int* __restrict__ dst,
                                                const int* __restrict__ ea,
                                                const int* __restrict__ baseBB,
                                                uint2* __restrict__ staged,
                                                int E, int chunk, int nbuck){
  __shared__ int run[512];
  int b = blockIdx.x;
  for (int i = threadIdx.x; i < nbuck; i += 256) run[i] = baseBB[i*NBLK + b];
  __syncthreads();
  int e0 = b*chunk, e1 = min(e0 + chunk, E);
  for (int e = e0 + threadIdx.x; e < e1; e += 256){
    int d = dst[e];
    unsigned pv = ((unsigned)(ea[2*e]*3 + ea[2*e+1]) << 20) | (unsigned)src[e];
    int pos = atomicAdd(&run[d >> BUCKSH], 1);
    uint2 s; s.x = pv; s.y = (unsigned)d;
    staged[pos] = s;
  }
}

__global__ __launch_bounds__(256) void part_emit(const uint2* __restrict__ staged,
                                                 const int* __restrict__ baseBB,
                                                 unsigned* __restrict__ packed,
                                                 int* __restrict__ rowptr,
                                                 int N, int E, int nbuck, int M){
  __shared__ int ncnt[256];
  __shared__ int sscan[256];
  __shared__ int basep[256];
  __shared__ int cur[256];
  int k = blockIdx.x;
  int tid = threadIdx.x;
  int bstart = baseBB[k*NBLK];
  int bend = (k+1 < nbuck) ? baseBB[(k+1)*NBLK] : baseBB[M];
  ncnt[tid] = 0; cur[tid] = 0;
  __syncthreads();
  for (int j = bstart + tid; j < bend; j += 256)
    atomicAdd(&ncnt[staged[j].y & 255], 1);
  __syncthreads();
  int v = ncnt[tid];
  sscan[tid] = v;
  __syncthreads();
  #pragma unroll
  for (int off = 1; off < 256; off <<= 1){
    int t = (tid >= off) ? sscan[tid-off] : 0;
    __syncthreads();
    sscan[tid] += t;
    __syncthreads();
  }
  int excl = sscan[tid] - v;
  basep[tid] = bstart + excl;
  int node = k*256 + tid;
  if (node < N) rowptr[node] = bstart + excl;
  if (k == nbuck-1 && tid == 0) rowptr[N] = E;
  __syncthreads();
  for (int j = bstart + tid; j < bend; j += 256){
    uint2 s = staged[j];
    int dloc = (int)(s.y & 255);
    int pos = basep[dloc] + atomicAdd(&cur[dloc], 1);
    packed[pos] = s.x;
  }
}

// ---------------- input embedding (fp16 h) ----------------
__global__ void embed_kernel(const int* __restrict__ x, const float* __restrict__ xemb,
                             _Float16* __restrict__ h, int N){
  int t = blockIdx.x*256 + threadIdx.x;
  if (t >= N*16) return;
  int n = t >> 4, c = (t & 15) * 8;
  int x0 = x[2*n], x1 = x[2*n+1];
  const float* r0 = xemb + (size_t)x0*D + c;
  const float* r1 = xemb + (size_t)(120 + x1)*D + c;
  half8 o;
  #pragma unroll
  for (int j = 0; j < 8; ++j) o[j] = (_Float16)(r0[j] + r1[j]);
  *(half8*)(h + (size_t)n*D + c) = o;
}

// ---------------- per-layer constant tables ----------------
__global__ void prep_tables(const float* __restrict__ etab, const float* __restrict__ gamma,
                            const float* __restrict__ beta, const float* __restrict__ mean,
                            const float* __restrict__ var, const float* __restrict__ b2,
                            float* __restrict__ comb, float* __restrict__ sc, float* __restrict__ sh){
  int l = blockIdx.x, d = threadIdx.x;
  const float* et = etab + (size_t)l*9*D;
  float* cl = comb + (size_t)l*10*D;
  #pragma unroll
  for (int b = 0; b < 3; ++b)
    #pragma unroll
    for (int dd = 0; dd < 3; ++dd)
      cl[(b*3+dd)*D + d] = et[b*D + d] + et[(6+dd)*D + d];
  cl[9*D + d] = et[4*D + d] + et[6*D + d];
  float A = gamma[l*D+d] * rsqrtf(var[l*D+d] + 1e-5f);
  sc[l*D+d] = A;
  sh[l*D+d] = (b2[l*D+d] - mean[l*D+d]) * A + beta[l*D+d];
}

// repack weights fragment-major for coalesced B loads
__global__ void repack_weights(const float* __restrict__ w1, const float* __restrict__ w2,
                               _Float16* __restrict__ w1f, _Float16* __restrict__ w2f, int total){
  int i = blockIdx.x*256 + threadIdx.x;
  if (i >= total) return;                 // total = 5*H*D
  int l = i / (H*D), r = i % (H*D);
  {
    int n = r / D, k = r % D;
    w1f[(size_t)l*H*D + (size_t)(k>>3)*(H*8) + n*8 + (k&7)] = (_Float16)w1[i];
  }
  {
    int n2 = r / H, k2 = r % H;
    w2f[(size_t)l*D*H + (size_t)(k2>>3)*(D*8) + n2*8 + (k2&7)] = (_Float16)w2[i];
  }
}

// ---------------- aggregation: one wave per node, fp16, 16 gathers in flight ----------------
__global__ __launch_bounds__(256) void agg_kernel(
    const _Float16* __restrict__ h, const unsigned* __restrict__ packed,
    const int* __restrict__ rowptr, const float* __restrict__ comb,
    _Float16* __restrict__ agg, int N){
  __shared__ float cl[10*D];
  int tid = threadIdx.x;
  for (int i = tid; i < 10*D; i += 256) cl[i] = comb[i];
  __syncthreads();
  int node = __builtin_amdgcn_readfirstlane(blockIdx.x*4 + (tid >> 6)); // wave-uniform
  if (node >= N) return;
  int lane = tid & 63;
  int c = lane * 2;
  half2v hv = *(const half2v*)(h + (size_t)node*D + c);
  float ax = (float)hv.x + cl[9*D + c];
  float ay = (float)hv.y + cl[9*D + c + 1];
  int beg = rowptr[node], end = rowptr[node+1];
  unsigned long long cp = 0;             // 9 codes x 7-bit counters
  for (int j = beg; j < end; j += 16){
    int m = end - j;                     // wave-uniform
    unsigned p[16];
    #pragma unroll
    for (int k = 0; k < 16; ++k) if (k < m) p[k] = packed[j+k];
    half2v v[16];
    #pragma unroll
    for (int k = 0; k < 16; ++k) if (k < m)
      v[k] = *(const half2v*)(h + (size_t)(p[k] & 0xFFFFFu)*D + c);
    #pragma unroll
    for (int k = 0; k < 16; ++k) if (k < m){
      cp += 1ULL << (7*(int)(p[k] >> 20));
      ax += (float)v[k].x;
      ay += (float)v[k].y;
    }
  }
  #pragma unroll
  for (int cd = 0; cd < 9; ++cd){
    float cnt = (float)(int)((cp >> (7*cd)) & 127);
    ax += cnt * cl[cd*D + c];
    ay += cnt * cl[cd*D + c + 1];
  }
  half2v o; o.x = (_Float16)ax; o.y = (_Float16)ay;
  *(half2v*)(agg + (size_t)node*D + c) = o;
}

// ---------------- fused GIN MLP: stage A->LDS(swizzled), GEMM1+ReLU -> GEMM2+BN --------
__global__ __launch_bounds__(256) void mlp_kernel(
    const _Float16* __restrict__ agg, const _Float16* __restrict__ w1f,
    const _Float16* __restrict__ w2f, const float* __restrict__ b1,
    const float* __restrict__ sc, const float* __restrict__ sh,
    _Float16* __restrict__ hout, float* __restrict__ fout,
    int N, int relu_out){
  __shared__ __align__(16) char smem[64*256*2];
  _Float16* atile = (_Float16*)smem;   // row*128 + (c8 ^ (row&15))*8 + (col&7)
  _Float16* hmid  = (_Float16*)smem;   // row*256 + (c8 ^ (row&31))*8 + (col&7)
  int tid = threadIdx.x;
  int wave = tid >> 6, lane = tid & 63;
  int quad = lane >> 4, l15 = lane & 15;
  int r0 = blockIdx.x * 64;

  half8 zf;
  #pragma unroll
  for (int j = 0; j < 8; ++j) zf[j] = (_Float16)0.f;

  #pragma unroll
  for (int i = 0; i < 4; ++i){
    int ci = i*256 + tid;
    int row = ci >> 4, c8 = ci & 15;
    int m = r0 + row;
    half8 v = (m < N) ? *(const half8*)(agg + (size_t)m*D + c8*8) : zf;
    *(half8*)(atile + row*128 + ((c8 ^ (row & 15)) * 8)) = v;
  }
  __syncthreads();

  floatx4 acc[4][4] = {};
  half8 bcur[4], bnxt[4];
  #pragma unroll
  for (int nt = 0; nt < 4; ++nt)
    bcur[nt] = *(const half8*)(w1f + (size_t)quad*(H*8) + (wave*64 + nt*16 + l15)*8);
  #pragma unroll
  for (int ks = 0; ks < 4; ++ks){
    if (ks < 3){
      #pragma unroll
      for (int nt = 0; nt < 4; ++nt)
        bnxt[nt] = *(const half8*)(w1f + (size_t)((ks+1)*4 + quad)*(H*8) + (wave*64 + nt*16 + l15)*8);
    }
    int c8 = ks*4 + quad;
    half8 af[4];
    #pragma unroll
    for (int mt = 0; mt < 4; ++mt)
      af[mt] = *(const half8*)(atile + (mt*16 + l15)*128 + ((c8 ^ l15) * 8));
    #pragma unroll
    for (int mt = 0; mt < 4; ++mt)
      #pragma unroll
      for (int nt = 0; nt < 4; ++nt)
        acc[mt][nt] = __builtin_amdgcn_mfma_f32_16x16x32_f16(af[mt], bcur[nt], acc[mt][nt], 0, 0, 0);
    #pragma unroll
    for (int nt = 0; nt < 4; ++nt) bcur[nt] = bnxt[nt];
  }
  __syncthreads();

  #pragma unroll
  for (int nt = 0; nt < 4; ++nt){
    int n = wave*64 + nt*16 + l15;
    float bias = b1[n];
    #pragma unroll
    for (int mt = 0; mt < 4; ++mt)
      #pragma unroll
      for (int r = 0; r < 4; ++r){
        int row = mt*16 + quad*4 + r;
        hmid[row*256 + (((n >> 3) ^ (row & 31)) * 8) + (n & 7)] =
            (_Float16)fmaxf(acc[mt][nt][r] + bias, 0.f);
      }
  }
  __syncthreads();

  floatx4 acc2[4][2] = {};
  half8 gcur[2], gnxt[2];
  #pragma unroll
  for (int nt = 0; nt < 2; ++nt)
    gcur[nt] = *(const half8*)(w2f + (size_t)quad*(D*8) + (wave*32 + nt*16 + l15)*8);
  #pragma unroll
  for (int ks = 0; ks < 8; ++ks){
    if (ks < 7){
      #pragma unroll
      for (int nt = 0; nt < 2; ++nt)
        gnxt[nt] = *(const half8*)(w2f + (size_t)((ks+1)*4 + quad)*(D*8) + (wave*32 + nt*16 + l15)*8);
    }
    int c8 = ks*4 + quad;
    half8 af[4];
    #pragma unroll
    for (int mt = 0; mt < 4; ++mt){
      int row = mt*16 + l15;
      af[mt] = *(const half8*)(hmid + row*256 + ((c8 ^ (row & 31)) * 8));
    }
    #pragma unroll
    for (int mt = 0; mt < 4; ++mt)
      #pragma unroll
      for (int nt = 0; nt < 2; ++nt)
        acc2[mt][nt] = __builtin_amdgcn_mfma_f32_16x16x32_f16(af[mt], gcur[nt], acc2[mt][nt], 0, 0, 0);
    #pragma unroll
    for (int nt = 0; nt < 2; ++nt) gcur[nt] = gnxt[nt];
  }

  #pragma unroll
  for (int nt = 0; nt < 2; ++nt){
    int n = wave*32 + nt*16 + l15;
    float A = sc[n], B = sh[n];
    #pragma unroll
    for (int mt = 0; mt < 4; ++mt)
      #pragma unroll
      for (int r = 0; r < 4; ++r){
        int row = r0 + mt*16 + quad*4 + r;
        if (row < N){
          float v = acc2[mt][nt][r]*A + B;
          if (relu_out) v = fmaxf(v, 0.f);
          if (fout) fout[(size_t)row*D + n] = v;
          else      hout[(size_t)row*D + n] = (_Float16)v;
        }
      }
  }
}

extern "C" void kernel_launch(void* const* d_in, const int* in_sizes, int n_in,
                              void* d_out, int out_size, void* d_ws, size_t ws_size,
                              hipStream_t stream){
  const int*   x     = (const int*)d_in[0];
  const int*   ei    = (const int*)d_in[1];
  const int*   ea    = (const int*)d_in[2];
  const float* xemb  = (const float*)d_in[3];
  const float* etab  = (const float*)d_in[4];
  const float* w1    = (const float*)d_in[5];
  const float* b1    = (const float*)d_in[6];
  const float* w2    = (const float*)d_in[7];
  const float* b2    = (const float*)d_in[8];
  const float* gamma = (const float*)d_in[9];
  const float* beta  = (const float*)d_in[10];
  const float* mean  = (const float*)d_in[11];
  const float* var   = (const float*)d_in[12];
  float* out = (float*)d_out;

  int N = in_sizes[0] / 2;
  int E = in_sizes[1] / 2;
  int nbuck = (N + 255) >> 8;
  int M = nbuck * NBLK;
  int nbM = (M + 1023) / 1024;
  int chunk = (E + NBLK - 1) / NBLK;

  char* ws = (char*)d_ws;
  size_t off = 0;
  auto alloc = [&](size_t b){ void* p = ws + off; off += (b + 255) & ~(size_t)255; return p; };
  _Float16* h      = (_Float16*)alloc((size_t)N*D*2);
  _Float16* agg    = (_Float16*)alloc((size_t)N*D*2);    // staged aliases this (E*8 <= N*D*2)
  unsigned* packed = (unsigned*)alloc((size_t)(E+16)*4);
  int*      rowptr = (int*)alloc((size_t)(N+1)*4);
  int*      cntBB  = (int*)alloc((size_t)M*4);
  int*      baseBB = (int*)alloc((size_t)(M+1)*4);
  int*      bsum   = (int*)alloc((size_t)nbM*4);
  int*      bbase  = (int*)alloc((size_t)nbM*4);
  _Float16* w1f    = (_Float16*)alloc((size_t)5*H*D*2);
  _Float16* w2f    = (_Float16*)alloc((size_t)5*D*H*2);
  float*    comb   = (float*)alloc((size_t)5*10*D*4);
  float*    sc     = (float*)alloc((size_t)5*D*4);
  float*    sh     = (float*)alloc((size_t)5*D*4);
  uint2*    staged = (uint2*)agg;   // dead before agg_kernel first writes agg

  const int* srcp = ei;
  const int* dstp = ei + E;

  part_count<<<NBLK, 256, 0, stream>>>(dstp, cntBB, E, chunk, nbuck);
  scan_part <<<nbM, 256, 0, stream>>>(cntBB, bsum, M);
  scan_bsums<<<1, 1024, 0, stream>>>(bsum, bbase, baseBB, nbM, M);   // baseBB[M] = E
  scan_emit <<<nbM, 256, 0, stream>>>(cntBB, bbase, baseBB, M);
  part_bin  <<<NBLK, 256, 0, stream>>>(srcp, dstp, ea, baseBB, staged, E, chunk, nbuck);
  part_emit <<<nbuck, 256, 0, stream>>>(staged, baseBB, packed, rowptr, N, E, nbuck, M);
  repack_weights<<<(5*H*D+255)/256, 256, 0, stream>>>(w1, w2, w1f, w2f, 5*H*D);
  prep_tables<<<5, 128, 0, stream>>>(etab, gamma, beta, mean, var, b2, comb, sc, sh);
  embed_kernel<<<((size_t)N*16+255)/256, 256, 0, stream>>>(x, xemb, h, N);

  for (int l = 0; l < 5; ++l){
    agg_kernel<<<(N+3)/4, 256, 0, stream>>>(h, packed, rowptr, comb + (size_t)l*10*D, agg, N);
    int last = (l == 4);
    mlp_kernel<<<(N+63)/64, 256, 0, stream>>>(agg, w1f + (size_t)l*H*D, w2f + (size_t)l*D*H,
        b1 + (size_t)l*H, sc + (size_t)l*D, sh + (size_t)l*D,
        last ? (_Float16*)nullptr : h, last ? out : (float*)nullptr,
        N, last ? 0 : 1);
  }
}